// Round 17
// baseline (220.365 us; speedup 1.0000x reference)
//
#include <hip/hip_runtime.h>
#include <hip/hip_bf16.h>
#include <hip/hip_runtime_api.h>

// Problem constants (N=2, L=2048, D=1024, H=16, DH=64, kt=3)
// Inputs fp32, OUTPUT fp32 (proven R7+). Intermediates bf16 where cheap.
#define NB 2
#define LL 2048
#define DD 1024
#define HH 16
#define DH 64
#define ROWS (NB*LL)        // 4096

typedef short bf16x8 __attribute__((ext_vector_type(8)));   // 8 bf16 = 4 VGPRs
typedef float f32x4  __attribute__((ext_vector_type(4)));

__device__ inline float b2f(unsigned short u) {
    union { float f; unsigned int i; } c; c.i = ((unsigned int)u) << 16; return c.f;
}
__device__ inline unsigned short f2b(float f) {
    __hip_bfloat16 h = __float2bfloat16(f);
    union { __hip_bfloat16 h; unsigned short u; } c; c.h = h; return c.u;
}

// ---------------------------------------------------------------------------
// Fused cast (x, in_w q-part, in_w v-part, out_w -> bf16) + acc init.
// ---------------------------------------------------------------------------
__global__ __launch_bounds__(256) void fused_cast_init(const float* __restrict__ x,
                                                       const float* __restrict__ in_w,
                                                       const float* __restrict__ out_w,
                                                       __hip_bfloat16* __restrict__ xb,
                                                       __hip_bfloat16* __restrict__ wqb,
                                                       __hip_bfloat16* __restrict__ wvb,
                                                       __hip_bfloat16* __restrict__ owb,
                                                       float* __restrict__ q_rel,
                                                       float* __restrict__ absacc)
{
    const long idx = (long)blockIdx.x * 256 + threadIdx.x;
    const float4* src;
    __hip_bfloat16* dst;
    long off;
    if (idx < 1048576)      { src = (const float4*)x;     dst = xb;  off = idx; }
    else if (idx < 1310720) { src = (const float4*)in_w;  dst = wqb; off = idx - 1048576; }
    else if (idx < 1572864) { src = (const float4*)(in_w + (size_t)2 * DD * DD);
                              dst = wvb; off = idx - 1310720; }
    else                    { src = (const float4*)out_w; dst = owb; off = idx - 1572864; }

    const float4 v = src[off];
    union { short4 s; __hip_bfloat16 h[4]; } u;
    u.h[0] = __float2bfloat16(v.x);
    u.h[1] = __float2bfloat16(v.y);
    u.h[2] = __float2bfloat16(v.z);
    u.h[3] = __float2bfloat16(v.w);
    ((short4*)dst)[off] = u.s;

    if (blockIdx.x == 0) {
        for (int j = threadIdx.x; j < 32 * DH; j += 256) q_rel[j] = 0.f;
        if (threadIdx.x < 32) absacc[threadIdx.x] = 0.f;
    }
}

// ---------------------------------------------------------------------------
// Fused q|vT projection GEMM, BK=64 + XOR-swizzled LDS (proven R16).
// ---------------------------------------------------------------------------
__global__ __launch_bounds__(256) void gemm_qv(const __hip_bfloat16* __restrict__ A,
                                               const __hip_bfloat16* __restrict__ Bm,
                                               const float* __restrict__ in_b,
                                               __hip_bfloat16* __restrict__ q,
                                               __hip_bfloat16* __restrict__ vT)
{
    __shared__ short As[128 * 64];
    __shared__ short Bs[128 * 64];

    const int tid  = threadIdx.x;
    const int lane = tid & 63;
    const int w    = tid >> 6;
    const int wm   = w >> 1;
    const int wn   = w & 1;
    const int l15  = lane & 15;
    const int quad = lane >> 4;

    const int n0 = blockIdx.x * 128;
    const int m0 = blockIdx.y * 128;
    const int K  = DD;

    const int lrow = lane >> 3;
    const int sseg = ((lane & 7) + lrow) & 7;

    const __hip_bfloat16* gA0 = A  + (size_t)(m0 + w * 32 + lrow) * K + sseg * 8;
    const __hip_bfloat16* gB0 = Bm + (size_t)(n0 + w * 32 + lrow) * K + sseg * 8;

    f32x4 acc[4][4];
    #pragma unroll
    for (int i = 0; i < 4; ++i)
        #pragma unroll
        for (int j = 0; j < 4; ++j) acc[i][j] = {0.f, 0.f, 0.f, 0.f};

    for (int k0 = 0; k0 < K; k0 += 64) {
        __syncthreads();
        #pragma unroll
        for (int j = 0; j < 4; ++j) {
            __builtin_amdgcn_global_load_lds((const void*)(gA0 + (size_t)(j * 8) * K + k0),
                                             (void*)(As + (w * 32 + j * 8) * 64), 16, 0, 0);
            __builtin_amdgcn_global_load_lds((const void*)(gB0 + (size_t)(j * 8) * K + k0),
                                             (void*)(Bs + (w * 32 + j * 8) * 64), 16, 0, 0);
        }
        __syncthreads();

        #pragma unroll
        for (int c = 0; c < 2; ++c) {
            const int co = ((quad + c * 4 - l15) & 7) * 8;
            bf16x8 af[4], bf[4];
            #pragma unroll
            for (int mt = 0; mt < 4; ++mt)
                af[mt] = *(const bf16x8*)(As + (wm * 64 + mt * 16 + l15) * 64 + co);
            #pragma unroll
            for (int nt = 0; nt < 4; ++nt)
                bf[nt] = *(const bf16x8*)(Bs + (wn * 64 + nt * 16 + l15) * 64 + co);

            #pragma unroll
            for (int mt = 0; mt < 4; ++mt)
                #pragma unroll
                for (int nt = 0; nt < 4; ++nt)
                    acc[mt][nt] = __builtin_amdgcn_mfma_f32_16x16x32_bf16(
                        af[mt], bf[nt], acc[mt][nt], 0, 0, 0);
        }
    }

    #pragma unroll
    for (int nt = 0; nt < 4; ++nt) {
        const int colg = n0 + wn * 64 + nt * 16 + l15;
        const float bv = (colg < DD) ? in_b[colg] : in_b[DD + colg];
        if (colg < DD) {
            #pragma unroll
            for (int mt = 0; mt < 4; ++mt) {
                #pragma unroll
                for (int r = 0; r < 4; ++r) {
                    const int row = m0 + wm * 64 + mt * 16 + quad * 4 + r;
                    float v = acc[mt][nt][r] + bv;
                    v = isfinite(v) ? v : 0.f;
                    q[(size_t)row * DD + colg] = __float2bfloat16(v);
                }
            }
        } else {
            const int col = colg - DD;
            #pragma unroll
            for (int mt = 0; mt < 4; ++mt) {
                const int row0 = m0 + wm * 64 + mt * 16 + quad * 4;
                const int nn = row0 >> 11;
                const int l  = row0 & (LL - 1);
                ushort4 u;
                float v0 = acc[mt][nt][0] + bv; v0 = isfinite(v0) ? v0 : 0.f;
                float v1 = acc[mt][nt][1] + bv; v1 = isfinite(v1) ? v1 : 0.f;
                float v2 = acc[mt][nt][2] + bv; v2 = isfinite(v2) ? v2 : 0.f;
                float v3 = acc[mt][nt][3] + bv; v3 = isfinite(v3) ? v3 : 0.f;
                u.x = f2b(v0); u.y = f2b(v1); u.z = f2b(v2); u.w = f2b(v3);
                *(ushort4*)(vT + ((size_t)(nn * 1024 + col)) * LL + l) = u;
            }
        }
    }
}

// ---------------------------------------------------------------------------
// Out-projection GEMM, 128(M)x64(N), BK=64 + XOR-swizzled LDS (proven R16).
// Mock fill in block (0,0).
// ---------------------------------------------------------------------------
__global__ __launch_bounds__(256) void gemm_out64(const __hip_bfloat16* __restrict__ A,
                                                  const __hip_bfloat16* __restrict__ Bm,
                                                  const float* __restrict__ bias,
                                                  float* __restrict__ C,
                                                  float* __restrict__ mock)
{
    __shared__ short As[128 * 64];
    __shared__ short Bs[64 * 64];

    const int tid  = threadIdx.x;
    const int lane = tid & 63;
    const int w    = tid >> 6;
    const int l15  = lane & 15;
    const int quad = lane >> 4;

    const int n0 = blockIdx.x * 64;
    const int m0 = blockIdx.y * 128;
    const int K  = DD;

    const int lrow = lane >> 3;
    const int sseg = ((lane & 7) + lrow) & 7;

    const __hip_bfloat16* gA0 = A  + (size_t)(m0 + w * 32 + lrow) * K + sseg * 8;
    const __hip_bfloat16* gB0 = Bm + (size_t)(n0 + w * 16 + lrow) * K + sseg * 8;

    f32x4 acc[2][4];
    #pragma unroll
    for (int i = 0; i < 2; ++i)
        #pragma unroll
        for (int j = 0; j < 4; ++j) acc[i][j] = {0.f, 0.f, 0.f, 0.f};

    for (int k0 = 0; k0 < K; k0 += 64) {
        __syncthreads();
        #pragma unroll
        for (int j = 0; j < 4; ++j)
            __builtin_amdgcn_global_load_lds((const void*)(gA0 + (size_t)(j * 8) * K + k0),
                                             (void*)(As + (w * 32 + j * 8) * 64), 16, 0, 0);
        #pragma unroll
        for (int j = 0; j < 2; ++j)
            __builtin_amdgcn_global_load_lds((const void*)(gB0 + (size_t)(j * 8) * K + k0),
                                             (void*)(Bs + (w * 16 + j * 8) * 64), 16, 0, 0);
        __syncthreads();

        #pragma unroll
        for (int c = 0; c < 2; ++c) {
            const int co = ((quad + c * 4 - l15) & 7) * 8;
            bf16x8 af[2], bf[4];
            #pragma unroll
            for (int mt = 0; mt < 2; ++mt)
                af[mt] = *(const bf16x8*)(As + (w * 32 + mt * 16 + l15) * 64 + co);
            #pragma unroll
            for (int nt = 0; nt < 4; ++nt)
                bf[nt] = *(const bf16x8*)(Bs + (nt * 16 + l15) * 64 + co);

            #pragma unroll
            for (int mt = 0; mt < 2; ++mt)
                #pragma unroll
                for (int nt = 0; nt < 4; ++nt)
                    acc[mt][nt] = __builtin_amdgcn_mfma_f32_16x16x32_bf16(
                        af[mt], bf[nt], acc[mt][nt], 0, 0, 0);
        }
    }

    #pragma unroll
    for (int nt = 0; nt < 4; ++nt) {
        const int col = n0 + nt * 16 + l15;
        const float bv = bias[col];
        #pragma unroll
        for (int mt = 0; mt < 2; ++mt) {
            #pragma unroll
            for (int r = 0; r < 4; ++r) {
                const int row = m0 + w * 32 + mt * 16 + quad * 4 + r;
                float v = acc[mt][nt][r] + bv;
                v = isfinite(v) ? v : 0.f;
                C[(size_t)row * DD + col] = v;
            }
        }
    }

    if (mock != nullptr && blockIdx.x == 0 && blockIdx.y == 0) {
        for (int i = tid; i < NB * LL; i += 256) mock[i] = 1.0f / (float)LL;
    }
}

// ---------------------------------------------------------------------------
// K2: causal conv(3) + exact GeLU + LN(DH) + partial mean -> atomicAdd (R13).
// ---------------------------------------------------------------------------
__global__ __launch_bounds__(256) void conv_gelu_ln_part(const __hip_bfloat16* __restrict__ q,
                                                          const float* __restrict__ conv_w,
                                                          const float* __restrict__ conv_b,
                                                          const float* __restrict__ ln_g,
                                                          const float* __restrict__ ln_b,
                                                          float* __restrict__ q_rel)
{
    const int bx = blockIdx.x;
    const int nh = bx >> 4;
    const int lc = bx & 15;
    const int n  = nh >> 4;
    const int h  = nh & 15;
    const int tid = threadIdx.x;
    const int d   = tid & 63;
    const int wv  = tid >> 6;
    const int l0  = lc * 128;

    __shared__ unsigned short qs[130 * 64];
    __shared__ float red[4 * 64];

    for (int idx = tid; idx < 130 * 8; idx += 256) {
        const int r   = idx >> 3;
        const int seg = idx & 7;
        const int l   = l0 - 2 + r;
        uint4 val = {0u, 0u, 0u, 0u};
        if (l >= 0)
            val = *(const uint4*)(q + (size_t)(n * LL + l) * DD + h * DH + seg * 8);
        *(uint4*)(qs + r * 64 + seg * 8) = val;
    }
    __syncthreads();

    const float w0 = conv_w[d * 3 + 0];
    const float w1 = conv_w[d * 3 + 1];
    const float w2 = conv_w[d * 3 + 2];
    const float cb = conv_b[d];
    const float lg = ln_g[d];
    const float lb = ln_b[d];

    float part = 0.f;
    for (int i = 0; i < 32; ++i) {
        const int r = wv * 32 + i + 2;
        const float xm2 = b2f(qs[(r - 2) * 64 + d]);
        const float xm1 = b2f(qs[(r - 1) * 64 + d]);
        const float x0  = b2f(qs[r * 64 + d]);
        const float c   = cb + w0 * xm2 + w1 * xm1 + w2 * x0;
        const float g   = 0.5f * c * (1.f + erff(c * 0.70710678118654752f));

        float s = g;
        #pragma unroll
        for (int off = 32; off > 0; off >>= 1) s += __shfl_xor(s, off);
        const float mu = s * (1.f / 64.f);

        const float dg = g - mu;
        float s2 = dg * dg;
        #pragma unroll
        for (int off = 32; off > 0; off >>= 1) s2 += __shfl_xor(s2, off);
        const float var = s2 * (1.f / 64.f);

        part += dg * rsqrtf(var + 1e-5f) * lg + lb;
    }

    red[wv * 64 + d] = part;
    __syncthreads();
    if (tid < 64) {
        const float t = red[d] + red[64 + d] + red[128 + d] + red[192 + d];
        atomicAdd(&q_rel[nh * DH + d], t * (0.125f / (float)LL));
    }
}

// ---------------------------------------------------------------------------
// K2b: fold k-projection; grid 128 (nh x 4 col-chunks of 256) (proven R13).
// ---------------------------------------------------------------------------
__global__ __launch_bounds__(256) void proj_p2(const float* __restrict__ in_w,
                                               const float* __restrict__ in_b,
                                               const float* __restrict__ q_rel,
                                               __hip_bfloat16* __restrict__ pb,
                                               float* __restrict__ beta)
{
    const int bx = blockIdx.x;
    const int nh = bx >> 2;
    const int cc = bx & 3;
    const int h  = nh & 15;
    const int tid = threadIdx.x;

    __shared__ float qs[64];
    if (tid < 64) qs[tid] = q_rel[nh * DH + tid];
    __syncthreads();

    const float* W = in_w + ((size_t)DD + h * DH) * DD;
    const int c = cc * 256 + tid;
    float a = 0.f;
    #pragma unroll 8
    for (int d = 0; d < 64; ++d)
        a += qs[d] * W[(size_t)d * DD + c];
    pb[(size_t)nh * DD + c] = __float2bfloat16(a);

    if (cc == 0 && tid < 64) {
        float b = qs[tid] * in_b[DD + h * DH + tid];
        #pragma unroll
        for (int off = 32; off > 0; off >>= 1) b += __shfl_xor(b, off);
        if (tid == 0) beta[nh] = b;
    }
}

// ---------------------------------------------------------------------------
// K3: Wk as tall-skinny MFMA GEMM (proven R14-R16).
// ---------------------------------------------------------------------------
__global__ __launch_bounds__(256) void wk_mfma(const __hip_bfloat16* __restrict__ xb,
                                               const __hip_bfloat16* __restrict__ pb,
                                               const float* __restrict__ beta,
                                               float* __restrict__ WnRaw,
                                               float* __restrict__ absacc)
{
    __shared__ short As[128 * 32];
    __shared__ short Bs[16 * 32];

    const int bx   = blockIdx.x;
    const int n    = bx >> 4;
    const int lt   = bx & 15;
    const int tid  = threadIdx.x;
    const int lane = tid & 63;
    const int w    = tid >> 6;
    const int l15  = lane & 15;
    const int quad = lane >> 4;
    const int m0   = lt * 128;

    const int lr  = lane >> 2;
    const int lsg = lane & 3;

    const __hip_bfloat16* gA0 = xb + (size_t)(n * LL + m0 + w * 32 + lr) * DD + lsg * 8;
    const __hip_bfloat16* gB0 = pb + (size_t)(n * 16 + lr) * DD + lsg * 8;
    short* lA0 = As + (w * 32) * 32;
    short* lA1 = As + (w * 32 + 16) * 32;

    f32x4 acc0 = {0.f,0.f,0.f,0.f};
    f32x4 acc1 = {0.f,0.f,0.f,0.f};

    for (int k0 = 0; k0 < DD; k0 += 32) {
        __syncthreads();
        __builtin_amdgcn_global_load_lds((const void*)(gA0 + k0),                   (void*)lA0, 16, 0, 0);
        __builtin_amdgcn_global_load_lds((const void*)(gA0 + (size_t)16 * DD + k0), (void*)lA1, 16, 0, 0);
        if (w == 0)
            __builtin_amdgcn_global_load_lds((const void*)(gB0 + k0), (void*)Bs, 16, 0, 0);
        __syncthreads();

        bf16x8 a0 = *(const bf16x8*)(As + (w * 32 + l15) * 32 + quad * 8);
        bf16x8 a1 = *(const bf16x8*)(As + (w * 32 + 16 + l15) * 32 + quad * 8);
        bf16x8 b  = *(const bf16x8*)(Bs + l15 * 32 + quad * 8);

        acc0 = __builtin_amdgcn_mfma_f32_16x16x32_bf16(a0, b, acc0, 0, 0, 0);
        acc1 = __builtin_amdgcn_mfma_f32_16x16x32_bf16(a1, b, acc1, 0, 0, 0);
    }

    const int hd = n * 16 + l15;
    const float bet = beta[hd];
    float asum = 0.f;
    f32x4 accs[2] = {acc0, acc1};
    #pragma unroll
    for (int mt = 0; mt < 2; ++mt) {
        #pragma unroll
        for (int r = 0; r < 4; ++r) {
            const int l = m0 + w * 32 + mt * 16 + quad * 4 + r;
            float v = accs[mt][r] + bet;
            v = isfinite(v) ? v : 0.f;
            WnRaw[(size_t)hd * LL + l] = v;
            asum += fabsf(v);
        }
    }
    asum += __shfl_xor(asum, 16);
    asum += __shfl_xor(asum, 32);
    if (quad == 0) atomicAdd(&absacc[hd], asum);
}

// ---------------------------------------------------------------------------
// K4: QUAD-tile MFMA Toeplitz: block covers t in [t0b, t0b+256) (four 64-row
// tiles) -> 32 MFMAs per barrier, grid 256 = 1 block/CU (fully resident).
// Tiles past their own diagonal accumulate exact zeros via the zero-padded
// window (offset 255; lag = i-255) -> bit-identical to the pair version.
// v-staging / XOR swizzle / double-buffer verbatim from R15/R16.
// ---------------------------------------------------------------------------
__global__ __launch_bounds__(256) void toeplitz4(const __hip_bfloat16* __restrict__ vT,
                                                 const float* __restrict__ WnRaw,
                                                 const float* __restrict__ absacc,
                                                 __hip_bfloat16* __restrict__ merged)
{
    const int bx = blockIdx.x;
    const int a  = 7 - (bx >> 5);       // quad index, heavy first
    const int nh = bx & 31;
    const int n  = nh >> 4;
    const int h  = nh & 15;
    const int tid  = threadIdx.x;
    const int lane = tid & 63;
    const int w    = tid >> 6;
    const int l15  = lane & 15;
    const int quad = lane >> 4;
    const int t0b  = a * 256;
    const int tthi = 4 * a + 3;         // last s-tile index

    __shared__ unsigned short wfull[2560];      // wfull[i] = Wn_norm[i-255]
    __shared__ unsigned short vbuf[2][64 * 64];

    const float inv = 1.f / (absacc[nh] + 1e-6f);
    const float* wnr = WnRaw + (size_t)nh * LL;
    const __hip_bfloat16* vtb = vT + (size_t)nh * 64 * LL;

    const int wlim = t0b + 512;
    for (int i = tid; i < wlim; i += 256) {
        const int lag = i - 255;
        wfull[i] = f2b(lag >= 0 ? wnr[lag] * inv : 0.f);
    }

    const int srow = lane >> 3;
    const int sseg = ((lane & 7) + srow) & 7;

    #pragma unroll
    for (int j = 0; j < 2; ++j) {
        const int r0 = w * 16 + j * 8;
        __builtin_amdgcn_global_load_lds(
            (const void*)(vtb + (size_t)(r0 + srow) * LL + sseg * 8),
            (void*)(&vbuf[0][r0 * 64]), 16, 0, 0);
    }

    f32x4 acc[4][4];    // [t-tile][col-tile]
    #pragma unroll
    for (int i = 0; i < 4; ++i)
        #pragma unroll
        for (int j = 0; j < 4; ++j) acc[i][j] = {0.f,0.f,0.f,0.f};

    int cur = 0;
    __syncthreads();
    for (int st = 0; st <= tthi; ++st) {
        if (st < tthi) {
            const int s0n = (st + 1) * 64;
            #pragma unroll
            for (int j = 0; j < 2; ++j) {
                const int r0 = w * 16 + j * 8;
                __builtin_amdgcn_global_load_lds(
                    (const void*)(vtb + (size_t)(r0 + srow) * LL + s0n + sseg * 8),
                    (void*)(&vbuf[cur ^ 1][r0 * 64]), 16, 0, 0);
            }
        }
        const int dL = t0b - st * 64;        // lowest tile's delta
        const unsigned short* vb = vbuf[cur];

        #pragma unroll
        for (int c = 0; c < 2; ++c) {
            union { bf16x8 v8; unsigned short u[8]; } af[4];
            const int I0 = 255 + (w * 16 + l15) - c * 32 - quad * 8 + dL;
            #pragma unroll
            for (int t = 0; t < 4; ++t) {
                const int It = I0 + 64 * t;
                #pragma unroll
                for (int j = 0; j < 8; ++j) af[t].u[j] = wfull[It - j];
            }

            const int seg = c * 4 + quad;
            const int co  = ((seg - l15) & 7) * 8;
            bf16x8 bf0 = *(const bf16x8*)(vb + (0  + l15) * 64 + co);
            bf16x8 bf1 = *(const bf16x8*)(vb + (16 + l15) * 64 + co);
            bf16x8 bf2 = *(const bf16x8*)(vb + (32 + l15) * 64 + co);
            bf16x8 bf3 = *(const bf16x8*)(vb + (48 + l15) * 64 + co);

            #pragma unroll
            for (int t = 0; t < 4; ++t) {
                acc[t][0] = __builtin_amdgcn_mfma_f32_16x16x32_bf16(af[t].v8, bf0, acc[t][0], 0, 0, 0);
                acc[t][1] = __builtin_amdgcn_mfma_f32_16x16x32_bf16(af[t].v8, bf1, acc[t][1], 0, 0, 0);
                acc[t][2] = __builtin_amdgcn_mfma_f32_16x16x32_bf16(af[t].v8, bf2, acc[t][2], 0, 0, 0);
                acc[t][3] = __builtin_amdgcn_mfma_f32_16x16x32_bf16(af[t].v8, bf3, acc[t][3], 0, 0, 0);
            }
        }
        __syncthreads();
        cur ^= 1;
    }

    #pragma unroll
    for (int t = 0; t < 4; ++t) {
        #pragma unroll
        for (int ct = 0; ct < 4; ++ct) {
            const int col = ct * 16 + l15;
            #pragma unroll
            for (int r = 0; r < 4; ++r) {
                const int tt = t0b + 64 * t + w * 16 + quad * 4 + r;
                merged[(size_t)(n * LL + tt) * DD + h * DH + col] = __float2bfloat16(acc[t][ct][r]);
            }
        }
    }
}

// ---------------------------------------------------------------------------
// Buffers (ws ~14.8MB < proven 17.05MB):
//   ws: xb bf16 8.39M (x -> merged), wqb 2.10M, wvb 2.10M, owb 2.10M,
//       WnRaw 256K, q_rel 8K, pb bf16 64K, beta 128B
//   d_out: [0,8.39M) q bf16; [8.39M,16.78M) vT bf16; absacc in out2 tail;
//          final fp32 output + mock overwrite everything at the end.
// ---------------------------------------------------------------------------
extern "C" void kernel_launch(void* const* d_in, const int* in_sizes, int n_in,
                              void* d_out, int out_size, void* d_ws, size_t ws_size,
                              hipStream_t stream)
{
    const float* x      = (const float*)d_in[0];
    const float* in_w   = (const float*)d_in[1];
    const float* in_b   = (const float*)d_in[2];
    const float* conv_w = (const float*)d_in[3];
    const float* conv_b = (const float*)d_in[4];
    const float* ln_g   = (const float*)d_in[5];
    const float* ln_b   = (const float*)d_in[6];
    const float* out_w  = (const float*)d_in[7];
    const float* out_b  = (const float*)d_in[8];

    __hip_bfloat16* xb    = (__hip_bfloat16*)d_ws;
    __hip_bfloat16* wqb   = xb + (size_t)ROWS * DD;
    __hip_bfloat16* wvb   = wqb + (size_t)DD * DD;     // contiguous after wqb
    __hip_bfloat16* owb   = wvb + (size_t)DD * DD;
    float*          WnRaw = (float*)(owb + (size_t)DD * DD);
    float*          q_rel = WnRaw + 32 * LL;
    __hip_bfloat16* pb    = (__hip_bfloat16*)(q_rel + 32 * DH);
    float*          beta  = (float*)(pb + 32 * DD);

    __hip_bfloat16* qbuf   = (__hip_bfloat16*)d_out;                     // low half
    __hip_bfloat16* vTbuf  = (__hip_bfloat16*)d_out + (size_t)ROWS * DD; // high half
    __hip_bfloat16* merged = xb;            // merged over dead x
    float*          out    = (float*)d_out;
    float*          out2   = out + (size_t)ROWS * DD;
    float*          absacc = out2;          // 32 floats, dead until mock fill

    // K0: fused casts + acc init
    fused_cast_init<<<7168, 256, 0, stream>>>(x, in_w, out_w, xb, wqb, wvb, owb,
                                              q_rel, absacc);

    // K1: fused q|vT projection (512 blocks = 2/CU, BK=64 swizzled)
    gemm_qv<<<dim3(2048 / 128, ROWS / 128), 256, 0, stream>>>(
        xb, wqb, in_b, qbuf, vTbuf);

    // K2: conv+gelu+LN partials -> q_rel (grid 512)
    conv_gelu_ln_part<<<512, 256, 0, stream>>>(qbuf, conv_w, conv_b, ln_g, ln_b, q_rel);

    // K2b: fold k-projection -> pb (bf16), beta (grid 128)
    proj_p2<<<128, 256, 0, stream>>>(in_w, in_b, q_rel, pb, beta);

    // K3: Wk as MFMA tall-skinny GEMM -> WnRaw + absacc (32 blocks)
    wk_mfma<<<32, 256, 0, stream>>>(xb, pb, beta, WnRaw, absacc);

    // K4: quad-tile MFMA Toeplitz -> merged (over dead x; 256 blocks = 1/CU)
    toeplitz4<<<256, 256, 0, stream>>>(vTbuf, WnRaw, absacc, merged);

    // K5: out = merged @ out_w^T + out_b (fp32, BK=64 swizzled) + mock fill
    gemm_out64<<<dim3(DD / 64, ROWS / 128), 256, 0, stream>>>(
        merged, owb, out_b, out, out2);
}